// Round 10
// baseline (401.323 us; speedup 1.0000x reference)
//
#include <hip/hip_runtime.h>
#include <hip/hip_bf16.h>
#include <math.h>

// ExpertPool: B=2,N=1024 -> T=2048 tokens, D=768, E=8, H=3072, top-K=2
#define T_TOK 2048
#define DIM   768
#define NEXP  8
#define HDIM  3072
#define MAXP  (T_TOK * 2)   // exactly 4096 (token,expert) pairs
#define NTILE_MAX 40        // sum ceil(cnt_e/128) <= 39

typedef __attribute__((ext_vector_type(8))) short bfrag;   // 8 bf16 (4 VGPRs)
typedef __attribute__((ext_vector_type(4))) float f32x4;   // MFMA C/D

__device__ __forceinline__ unsigned short f2bf(float f) {
  union { float f; unsigned int u; } x; x.f = f;
  unsigned int r = x.u + 0x7fffu + ((x.u >> 16) & 1u);  // RNE
  return (unsigned short)(r >> 16);
}

// async global->LDS 16B/lane. lds ptr must be WAVE-UNIFORM (HW: base + lane*16).
__device__ __forceinline__ void gload16(const void* g, void* lds_uniform) {
  __builtin_amdgcn_global_load_lds(
      (const __attribute__((address_space(1))) void*)g,
      (__attribute__((address_space(3))) void*)lds_uniform, 16, 0, 0);
}

// ---- fused prep: block 0 = routing (ballot-based, atomic-free);
//      blocks 1.. = fp32->bf16 streaming convert (~1.9 TB/s = measured ceiling
//      for this mixed stream; 3 shapes all identical).
__global__ void k_prep(const float* __restrict__ disp,
                       const float* __restrict__ comb,
                       int* __restrict__ meta,        // [0..7]=cnt [8..15]=off [16]=ntiles [17..56]=tiles
                       float* __restrict__ row_comb,
                       int* __restrict__ row_token,
                       int* __restrict__ tok2pair,    // (T_TOK,2)
                       const float* __restrict__ X, unsigned short* __restrict__ Xb,
                       const float* __restrict__ Wg, const float* __restrict__ Wv,
                       const float* __restrict__ Wo,
                       unsigned short* __restrict__ Wgh, unsigned short* __restrict__ Wvh,
                       unsigned short* __restrict__ Woh) {
  __shared__ int s_wsum[4];
  int b = blockIdx.x;
  int tid = threadIdx.x;
  if (b == 0) {
    int lane = tid & 63, wid = tid >> 6;
    unsigned long long lmask = (1ull << lane) - 1ull;
    int tn0 = 0, tn1 = 0, tn2 = 0, tn3 = 0, tn4 = 0, tn5 = 0, tn6 = 0, tn7 = 0;
    int run = 0;
#pragma unroll
    for (int e = 0; e < NEXP; ++e) {
      int off_e = run;
#pragma unroll
      for (int it = 0; it < 8; ++it) {
        int t = it * 256 + tid;
        bool pos = disp[t * NEXP + e] > 0.f;
        unsigned long long m = __ballot(pos);
        int lpfx = (int)__popcll(m & lmask);
        int wcnt = (int)__popcll(m);
        if (lane == 0) s_wsum[wid] = wcnt;
        __syncthreads();
        int w0 = s_wsum[0], w1 = s_wsum[1], w2 = s_wsum[2], w3 = s_wsum[3];
        int wbase = run + (wid > 0 ? w0 : 0) + (wid > 1 ? w1 : 0) + (wid > 2 ? w2 : 0);
        if (pos) {
          int p = wbase + lpfx;
          row_token[p] = t;
          row_comb[p] = comb[t * NEXP + e];
          int sl;
          if      (it == 0) { sl = tn0++; }
          else if (it == 1) { sl = tn1++; }
          else if (it == 2) { sl = tn2++; }
          else if (it == 3) { sl = tn3++; }
          else if (it == 4) { sl = tn4++; }
          else if (it == 5) { sl = tn5++; }
          else if (it == 6) { sl = tn6++; }
          else              { sl = tn7++; }
          tok2pair[t * 2 + sl] = p;
        }
        run += w0 + w1 + w2 + w3;
        __syncthreads();
      }
      if (tid == 0) { meta[e] = run - off_e; meta[NEXP + e] = off_e; }
    }
    if (tid == 0) {
      int nt = 0;
      for (int e = 0; e < NEXP; ++e) {
        int cnt = meta[e];
        for (int m0 = 0; m0 < cnt; m0 += 128)
          meta[17 + nt++] = (e << 16) | (m0 >> 7);
      }
      meta[16] = nt;
    }
    return;
  }
  // conversion blocks: 32768 fp32 elems each (16 chunks of 2048)
  int idx = b - 1;
  const float* src;
  unsigned short* dst;
  if (idx < 48)        { src = X;  dst = Xb;  }
  else if (idx < 624)  { src = Wg; dst = Wgh; idx -= 48;   }
  else if (idx < 1200) { src = Wv; dst = Wvh; idx -= 624;  }
  else                 { src = Wo; dst = Woh; idx -= 1200; }
  size_t base = (size_t)idx * 32768 + (size_t)tid * 8;
#pragma unroll
  for (int g = 0; g < 4; ++g) {
    float4 va[4], vb[4];
#pragma unroll
    for (int u = 0; u < 4; ++u) {
      size_t i = base + (size_t)(g * 4 + u) * 2048;
      va[u] = *(const float4*)(src + i);
      vb[u] = *(const float4*)(src + i + 4);
    }
#pragma unroll
    for (int u = 0; u < 4; ++u) {
      size_t i = base + (size_t)(g * 4 + u) * 2048;
      unsigned short r[8];
      r[0]=f2bf(va[u].x); r[1]=f2bf(va[u].y); r[2]=f2bf(va[u].z); r[3]=f2bf(va[u].w);
      r[4]=f2bf(vb[u].x); r[5]=f2bf(vb[u].y); r[6]=f2bf(vb[u].z); r[7]=f2bf(vb[u].w);
      *(uint4*)(dst + i) = *(uint4*)r;
    }
  }
}

// LDS layout for GEMMs: linear 64B rows (32 ushorts), 4x 16B slots per row.
// Swizzle: LDS slot s of row r holds element slot (s ^ swz(r)), swz(r)=(r^(r>>2))&3.
// gload_lds writes LINEAR dest; the swizzle is applied on the per-lane GLOBAL
// source address (m173) and on the fragment-read address (rule #21: both sides).

// ------- GEMM 1 fused: u = gelu(X@Wg^T) * (X@Wv^T) -> bf16 (P,H) -------
template<int WBF>
__global__ __launch_bounds__(256, 2) void k_gemm_gv_t(
    const unsigned short* __restrict__ Xb,  // (T_TOK, DIM) bf16
    const float* __restrict__ Wg,           // (NEXP, HDIM, DIM) fp32
    const float* __restrict__ Wv,
    const unsigned short* __restrict__ Wgh, // (NEXP, HDIM, DIM) bf16
    const unsigned short* __restrict__ Wvh,
    const int* __restrict__ meta,
    const int* __restrict__ row_token,
    unsigned short* __restrict__ ubuf)      // (MAXP, HDIM) bf16
{
  int blk = blockIdx.x;                     // 960 = 8 xcd * 3 strips * 40 tiles
  int xc = blk & 7, slot0 = blk >> 3;
  int nt = xc + 8 * (slot0 / NTILE_MAX);    // n-strip pinned to xcd
  int t  = slot0 % NTILE_MAX;
  if (t >= meta[16]) return;
  int tv = meta[17 + t];
  int e = tv >> 16, m0 = (tv & 0xffff) << 7;
  int cnt = meta[e], off = meta[NEXP + e];
  int n0 = nt * 128;

  __shared__ unsigned short As[128 * 32];   // 8 KB each, linear 64B rows
  __shared__ unsigned short Bgs[128 * 32];
  __shared__ unsigned short Bvs[128 * 32];

  int tid = threadIdx.x;
  int wid = tid >> 6, lane = tid & 63;
  int wm = (wid >> 1) * 64, wn = (wid & 1) * 64;
  int lr = lane & 15, quad = lane >> 4;
  // fragment-read slot: row = (16-mult) + lr -> swz(row) = (lr^(lr>>2))&3
  int qx = ((quad ^ (lr ^ (lr >> 2))) & 3) * 8;

  // staging geometry (2 rounds x 256 threads = 512 slots)
  int srow[2], ssub[2], a_tok[2];
#pragma unroll
  for (int r = 0; r < 2; ++r) {
    int s = tid + 256 * r;
    int row = s >> 2, sub = s & 3;
    srow[r] = row;
    ssub[r] = sub ^ ((row ^ (row >> 2)) & 3);
    int gr = m0 + row; if (gr >= cnt) gr = cnt - 1;
    a_tok[r] = row_token[off + gr];
  }

  const float* Wgb = Wg + (size_t)e * ((size_t)HDIM * DIM);
  const float* Wvb = Wv + (size_t)e * ((size_t)HDIM * DIM);
  const unsigned short* Wghb = Wgh + (size_t)e * ((size_t)HDIM * DIM);
  const unsigned short* Wvhb = Wvh + (size_t)e * ((size_t)HDIM * DIM);

  f32x4 zero4 = {0.f, 0.f, 0.f, 0.f};
  f32x4 accg[4][4], accv[4][4];
#pragma unroll
  for (int i = 0; i < 4; ++i)
#pragma unroll
    for (int j = 0; j < 4; ++j) { accg[i][j] = zero4; accv[i][j] = zero4; }

  for (int k0 = 0; k0 < DIM; k0 += 32) {
    __syncthreads();                       // prev iter's ds_reads done
    if constexpr (WBF) {
#pragma unroll
      for (int r = 0; r < 2; ++r) {
        int lb = (r * 256 + wid * 64) * 8; // wave-uniform LDS base (ushorts)
        gload16(Xb  + (size_t)a_tok[r] * DIM        + k0 + ssub[r] * 8, &As[lb]);
        gload16(Wghb + (size_t)(n0 + srow[r]) * DIM + k0 + ssub[r] * 8, &Bgs[lb]);
        gload16(Wvhb + (size_t)(n0 + srow[r]) * DIM + k0 + ssub[r] * 8, &Bvs[lb]);
      }
    } else {
#pragma unroll
      for (int r = 0; r < 2; ++r) {
        int sub = (tid + 256 * r) & 3;
        uint4 av = *(const uint4*)(Xb + (size_t)a_tok[r] * DIM + k0 + sub * 8);
        *(uint4*)(&As[srow[r] * 32 + ssub[r] * 8]) = av;
      }
#pragma unroll
      for (int r = 0; r < 4; ++r) {
        int c2 = tid + 256 * r;
        int row = c2 >> 3, c4 = c2 & 7;
        int sz2 = (row ^ (row >> 2)) & 3;
        int c4s = (((c4 >> 1) ^ sz2) << 1) | (c4 & 1);
        float4 gvv = *(const float4*)(Wgb + (size_t)(n0 + row) * DIM + k0 + c4 * 4);
        ushort4 gp;
        gp.x = f2bf(gvv.x); gp.y = f2bf(gvv.y); gp.z = f2bf(gvv.z); gp.w = f2bf(gvv.w);
        *(ushort4*)(&Bgs[row * 32 + c4s * 4]) = gp;
        float4 vvv = *(const float4*)(Wvb + (size_t)(n0 + row) * DIM + k0 + c4 * 4);
        ushort4 vp;
        vp.x = f2bf(vvv.x); vp.y = f2bf(vvv.y); vp.z = f2bf(vvv.z); vp.w = f2bf(vvv.w);
        *(ushort4*)(&Bvs[row * 32 + c4s * 4]) = vp;
      }
    }
    __syncthreads();                       // drains vmcnt -> tile ready
    bfrag a[4], bg[4], bv[4];
#pragma unroll
    for (int i = 0; i < 4; ++i)
      a[i] = *(const bfrag*)(&As[(wm + i * 16 + lr) * 32 + qx]);
#pragma unroll
    for (int j = 0; j < 4; ++j) {
      bg[j] = *(const bfrag*)(&Bgs[(wn + j * 16 + lr) * 32 + qx]);
      bv[j] = *(const bfrag*)(&Bvs[(wn + j * 16 + lr) * 32 + qx]);
    }
#pragma unroll
    for (int i = 0; i < 4; ++i)
#pragma unroll
      for (int j = 0; j < 4; ++j) {
        accg[i][j] = __builtin_amdgcn_mfma_f32_16x16x32_bf16(a[i], bg[j], accg[i][j], 0, 0, 0);
        accv[i][j] = __builtin_amdgcn_mfma_f32_16x16x32_bf16(a[i], bv[j], accv[i][j], 0, 0, 0);
      }
  }

  // epilogue: gelu_exact(g)*v on fp32 accumulators
#pragma unroll
  for (int i = 0; i < 4; ++i)
#pragma unroll
    for (int rg = 0; rg < 4; ++rg) {
      int gr = m0 + wm + i * 16 + quad * 4 + rg;
      if (gr < cnt) {
        size_t base = (size_t)(off + gr) * HDIM + n0 + wn;
#pragma unroll
        for (int j = 0; j < 4; ++j) {
          float g = accg[i][j][rg];
          float v = accv[i][j][rg];
          float u = 0.5f * g * (1.0f + erff(g * 0.70710678118654752f)) * v;
          ubuf[base + j * 16 + lr] = f2bf(u);
        }
      }
    }
}

// ------- GEMM 2: u @ Wo^T, split-K x4, strip-affinity remap over (nt,ks). -------
template<int WBF>
__global__ __launch_bounds__(256, 3) void k_gemm_out_t(
    const unsigned short* __restrict__ U,  // (MAXP, HDIM) bf16
    const float* __restrict__ Wo,          // (NEXP, DIM, HDIM) fp32
    const unsigned short* __restrict__ Woh,// (NEXP, DIM, HDIM) bf16
    const float* __restrict__ scale,
    const int* __restrict__ meta,
    const int* __restrict__ row_token,
    const float* __restrict__ row_comb,
    float* __restrict__ partial,           // (4, MAXP, DIM)
    float* __restrict__ out,               // (T_TOK, DIM)
    int mode)
{
  int blk = blockIdx.x;                    // 960 = 8 xcd * 3 strips * 40 tiles
  int xc = blk & 7, slot0 = blk >> 3;
  int sidx = xc + 8 * (slot0 / NTILE_MAX); // 0..23 strip index = (nt, ks)
  int nt = sidx % 6, ks = sidx / 6;
  int t = slot0 % NTILE_MAX;
  if (t >= meta[16]) return;
  int tv = meta[17 + t];
  int e = tv >> 16, m0 = (tv & 0xffff) << 7;
  int cnt = meta[e], off = meta[NEXP + e];
  int n0 = nt * 128;
  int kbase = ks * (HDIM / 4);

  __shared__ unsigned short As[128 * 32];
  __shared__ unsigned short Bs[128 * 32];

  int tid = threadIdx.x;
  int wid = tid >> 6, lane = tid & 63;
  int wm = (wid >> 1) * 64, wn = (wid & 1) * 64;
  int lr = lane & 15, quad = lane >> 4;
  int qx = ((quad ^ (lr ^ (lr >> 2))) & 3) * 8;

  int srow[2], ssub[2], a_grow[2];
#pragma unroll
  for (int r = 0; r < 2; ++r) {
    int s = tid + 256 * r;
    int row = s >> 2, sub = s & 3;
    srow[r] = row;
    ssub[r] = sub ^ ((row ^ (row >> 2)) & 3);
    int gr = m0 + row; if (gr >= cnt) gr = cnt - 1;
    a_grow[r] = off + gr;
  }

  const float* Wb = Wo + (size_t)e * ((size_t)DIM * HDIM);
  const unsigned short* Wbh = Woh + (size_t)e * ((size_t)DIM * HDIM);

  f32x4 zero4 = {0.f, 0.f, 0.f, 0.f};
  f32x4 acc[4][4];
#pragma unroll
  for (int i = 0; i < 4; ++i)
#pragma unroll
    for (int j = 0; j < 4; ++j) acc[i][j] = zero4;

  for (int kk = 0; kk < HDIM / 4; kk += 32) {
    int k0 = kbase + kk;
    __syncthreads();
    if constexpr (WBF) {
#pragma unroll
      for (int r = 0; r < 2; ++r) {
        int lb = (r * 256 + wid * 64) * 8;
        gload16(U   + (size_t)a_grow[r] * HDIM      + k0 + ssub[r] * 8, &As[lb]);
        gload16(Wbh + (size_t)(n0 + srow[r]) * HDIM + k0 + ssub[r] * 8, &Bs[lb]);
      }
    } else {
#pragma unroll
      for (int r = 0; r < 2; ++r) {
        int sub = (tid + 256 * r) & 3;
        uint4 av = *(const uint4*)(U + (size_t)a_grow[r] * HDIM + k0 + sub * 8);
        *(uint4*)(&As[srow[r] * 32 + ssub[r] * 8]) = av;
      }
#pragma unroll
      for (int r = 0; r < 4; ++r) {
        int c2 = tid + 256 * r;
        int row = c2 >> 3, c4 = c2 & 7;
        int sz2 = (row ^ (row >> 2)) & 3;
        int c4s = (((c4 >> 1) ^ sz2) << 1) | (c4 & 1);
        float4 bvv = *(const float4*)(Wb + (size_t)(n0 + row) * HDIM + k0 + c4 * 4);
        ushort4 bp;
        bp.x = f2bf(bvv.x); bp.y = f2bf(bvv.y); bp.z = f2bf(bvv.z); bp.w = f2bf(bvv.w);
        *(ushort4*)(&Bs[row * 32 + c4s * 4]) = bp;
      }
    }
    __syncthreads();
    bfrag a[4], b[4];
#pragma unroll
    for (int i = 0; i < 4; ++i)
      a[i] = *(const bfrag*)(&As[(wm + i * 16 + lr) * 32 + qx]);
#pragma unroll
    for (int j = 0; j < 4; ++j)
      b[j] = *(const bfrag*)(&Bs[(wn + j * 16 + lr) * 32 + qx]);
#pragma unroll
    for (int i = 0; i < 4; ++i)
#pragma unroll
      for (int j = 0; j < 4; ++j)
        acc[i][j] = __builtin_amdgcn_mfma_f32_16x16x32_bf16(a[i], b[j], acc[i][j], 0, 0, 0);
  }

  float sc = scale[e];
#pragma unroll
  for (int i = 0; i < 4; ++i)
#pragma unroll
    for (int rg = 0; rg < 4; ++rg) {
      int gr = m0 + wm + i * 16 + quad * 4 + rg;
      if (gr < cnt) {
        int grow = off + gr;
        float w = row_comb[grow] * sc;
        if (mode == 0) {
          float* pb = partial + ((size_t)ks * MAXP + grow) * DIM + n0 + wn;
#pragma unroll
          for (int j = 0; j < 4; ++j)
            pb[j * 16 + lr] = acc[i][j][rg] * w;
        } else {
          int tok = row_token[grow];
          float* ob = out + (size_t)tok * DIM + n0 + wn;
#pragma unroll
          for (int j = 0; j < 4; ++j)
            atomicAdd(ob + j * 16 + lr, acc[i][j][rg] * w);
        }
      }
    }
}

// ---------------- combine: out[t] = sum over 2 pairs x 4 K-splits ----------------
__global__ void k_combine(const float* __restrict__ partial,
                          const int* __restrict__ tok2pair,
                          float* __restrict__ out) {
  int idx = blockIdx.x * 256 + threadIdx.x;   // 2048 * 192 = 393216
  int t = idx / 192, d4 = idx % 192;
  int p0 = tok2pair[t * 2], p1 = tok2pair[t * 2 + 1];
  float sx = 0.f, sy = 0.f, sz = 0.f, sw = 0.f;
#pragma unroll
  for (int ks = 0; ks < 4; ++ks) {
    float4 a = *(const float4*)(partial + ((size_t)ks * MAXP + p0) * DIM + d4 * 4);
    float4 b = *(const float4*)(partial + ((size_t)ks * MAXP + p1) * DIM + d4 * 4);
    sx += a.x + b.x; sy += a.y + b.y; sz += a.z + b.z; sw += a.w + b.w;
  }
  float4 r; r.x = sx; r.y = sy; r.z = sz; r.w = sw;
  *(float4*)(out + (size_t)t * DIM + d4 * 4) = r;
}

extern "C" void kernel_launch(void* const* d_in, const int* in_sizes, int n_in,
                              void* d_out, int out_size, void* d_ws, size_t ws_size,
                              hipStream_t stream) {
  const float* tokens = (const float*)d_in[0];
  const float* disp   = (const float*)d_in[1];
  const float* comb   = (const float*)d_in[2];
  const float* Wg     = (const float*)d_in[3];
  const float* Wv     = (const float*)d_in[4];
  const float* Wo     = (const float*)d_in[5];
  const float* scale  = (const float*)d_in[6];
  float* out = (float*)d_out;

  char* ws = (char*)d_ws;
  int*   meta      = (int*)ws;                        // 57 ints
  int*   row_token = (int*)(ws + 16384);
  float* row_comb  = (float*)(ws + 32768);
  int*   tok2pair  = (int*)(ws + 49152);
  unsigned short* Xb   = (unsigned short*)(ws + (1ull << 20));          // 3 MB
  unsigned short* ubuf = (unsigned short*)(ws + (5ull << 20));          // 24 MB
  float* partial = (float*)(ws + (32ull << 20));                        // 48 MB

  // bf16 weight copies: each tensor 8*3072*768*2 B = 36 MiB.
  const size_t need_partial = (32ull << 20) + (size_t)4 * MAXP * DIM * sizeof(float); // 80 MiB
  const size_t need_full = 188ull << 20;   // 80 front + 3x36 weights
  const size_t need_mid  = 140ull << 20;   // 32 front (no partial) + 3x36

  int wbf, mode;
  unsigned short *Wgh = nullptr, *Wvh = nullptr, *Woh = nullptr;
  if (ws_size >= need_full) {
    wbf = 1; mode = 0;
    Wgh = (unsigned short*)(ws + (80ull  << 20));
    Wvh = (unsigned short*)(ws + (116ull << 20));
    Woh = (unsigned short*)(ws + (152ull << 20));
  } else if (ws_size >= need_mid) {
    wbf = 1; mode = 1;   // weights overlap partial space -> atomic combine
    Wgh = (unsigned short*)(ws + (32ull  << 20));
    Wvh = (unsigned short*)(ws + (68ull  << 20));
    Woh = (unsigned short*)(ws + (104ull << 20));
  } else {
    wbf = 0;
    mode = (ws_size >= need_partial) ? 0 : 1;
    Wgh = Wvh = Woh = (unsigned short*)Xb;  // unused by WBF=0 path
  }

  // fused routing + conversions (route block hides under conversion stream)
  int prep_grid = wbf ? (1 + 48 + 3 * 576) : (1 + 48);
  hipLaunchKernelGGL(k_prep, dim3(prep_grid), dim3(256), 0, stream,
                     disp, comb, meta, row_comb, row_token, tok2pair,
                     tokens, Xb, Wg, Wv, Wo, Wgh, Wvh, Woh);

  if (wbf)
    hipLaunchKernelGGL(HIP_KERNEL_NAME(k_gemm_gv_t<1>), dim3(NTILE_MAX * 24), dim3(256), 0, stream,
                       Xb, Wg, Wv, Wgh, Wvh, meta, row_token, ubuf);
  else
    hipLaunchKernelGGL(HIP_KERNEL_NAME(k_gemm_gv_t<0>), dim3(NTILE_MAX * 24), dim3(256), 0, stream,
                       Xb, Wg, Wv, Wgh, Wvh, meta, row_token, ubuf);

  if (mode == 1)
    hipMemsetAsync(d_out, 0, (size_t)out_size * sizeof(float), stream);

  if (wbf)
    hipLaunchKernelGGL(HIP_KERNEL_NAME(k_gemm_out_t<1>), dim3(NTILE_MAX * 6 * 4), dim3(256), 0, stream,
                       ubuf, Wo, Woh, scale, meta, row_token, row_comb, partial, out, mode);
  else
    hipLaunchKernelGGL(HIP_KERNEL_NAME(k_gemm_out_t<0>), dim3(NTILE_MAX * 6 * 4), dim3(256), 0, stream,
                       ubuf, Wo, Woh, scale, meta, row_token, row_comb, partial, out, mode);

  if (mode == 0)
    hipLaunchKernelGGL(k_combine, dim3((T_TOK * DIM / 4) / 256), dim3(256), 0, stream,
                       partial, tok2pair, out);
}